// Round 3
// baseline (222.460 us; speedup 1.0000x reference)
//
#include <hip/hip_runtime.h>

// Problem dims (fixed by reference setup_inputs)
#define BS   32
#define NF   64     // n_feat
#define NN   512    // N
#define JJ   4      // J
#define NOUT 128
#define CC   256    // J*NF
#define NC   16     // n-chunks (one block per (b,nc))
#define ROWS 32     // NN/NC rows per chunk
#define ROW4 512    // float4 per (b,n) row of W  (NN*JJ/4)

// Pre-kernel: out[b,o] = N * fc_b[o]  (overwrites the 0xAA poison; atomics
// from the fused kernel then accumulate on top). Grid 16 x 256 = 4096 = out_size.
__global__ __launch_bounds__(256) void bias_init_kernel(const float* __restrict__ fcb,
                                                        float* __restrict__ out) {
    int i = blockIdx.x * 256 + threadIdx.x;
    out[i] = (float)NN * fcb[i & (NOUT - 1)];
}

// Fused: per (b, n-chunk) block:
//   1) partial S[m,j] = sum_{n in chunk} W[b,n,m,j]        (streams W, the HBM cost)
//   2) partial T[j,f] = sum_m S[m,j] * X[b,f,m]            (X is L2-resident)
//   3) partial y[o]   = sum_c fc_w[o,c] * T[c]             (fc_w L2-resident)
//   4) atomicAdd into out[b,o]
__global__ __launch_bounds__(256) void fused_kernel(const float4* __restrict__ W4,
                                                    const float4* __restrict__ X4,
                                                    const float4* __restrict__ fcw4,
                                                    float* __restrict__ out) {
    // S stored [j][ms][mr], m = ms*128 + mr, padded to 132 so the ms-stride
    // rotates banks by 4 (no power-of-2 aliasing).
    __shared__ __align__(16) float S[JJ][4][132];
    __shared__ __align__(16) float Tp[4][CC];       // per-ms partial T, [ms][j*NF+f]
    __shared__ __align__(16) float4 Tsum4[CC / 4];  // final T as float4 over c

    int blk = blockIdx.x;           // b*NC + nc
    int nc  = blk & (NC - 1);
    int b   = blk >> 4;             // NC == 16
    int t   = threadIdx.x;

    // 1) Stream ROWS rows of W; each thread owns float4 columns t and t+256.
    //    One float4 at row-index m holds W[b,n,m,0..3] (j innermost).
    const float4* p = W4 + ((size_t)(b * NN + nc * ROWS)) * ROW4 + t;
    float4 a0 = make_float4(0.f, 0.f, 0.f, 0.f);
    float4 a1 = make_float4(0.f, 0.f, 0.f, 0.f);
#pragma unroll 8
    for (int r = 0; r < ROWS; ++r) {
        float4 v0 = p[(size_t)r * ROW4];
        float4 v1 = p[(size_t)r * ROW4 + 256];
        a0.x += v0.x; a0.y += v0.y; a0.z += v0.z; a0.w += v0.w;
        a1.x += v1.x; a1.y += v1.y; a1.z += v1.z; a1.w += v1.w;
    }
    {
        int ms = t >> 7, mr = t & 127;          // m = t      -> ms in {0,1}
        S[0][ms][mr] = a0.x; S[1][ms][mr] = a0.y;
        S[2][ms][mr] = a0.z; S[3][ms][mr] = a0.w;
        S[0][ms + 2][mr] = a1.x; S[1][ms + 2][mr] = a1.y;  // m = t+256 -> ms in {2,3}
        S[2][ms + 2][mr] = a1.z; S[3][ms + 2][mr] = a1.w;
    }
    __syncthreads();

    // 2) T[j][f] = sum_m S[j][m] * X[b,f,m], split over ms (4 m-ranges of 128).
    int f = t >> 2, ms = t & 3;
    const float4* xp = X4 + ((size_t)(b * NF + f)) * (NN / 4) + ms * 32;
    const float4* s0 = (const float4*)(&S[0][ms][0]);
    const float4* s1 = (const float4*)(&S[1][ms][0]);
    const float4* s2 = (const float4*)(&S[2][ms][0]);
    const float4* s3 = (const float4*)(&S[3][ms][0]);
    float t0 = 0.f, t1 = 0.f, t2 = 0.f, t3 = 0.f;
#pragma unroll 4
    for (int i = 0; i < 32; ++i) {
        float4 xv = xp[i];
        float4 b0 = s0[i], b1 = s1[i], b2 = s2[i], b3 = s3[i];
        t0 += xv.x * b0.x + xv.y * b0.y + xv.z * b0.z + xv.w * b0.w;
        t1 += xv.x * b1.x + xv.y * b1.y + xv.z * b1.z + xv.w * b1.w;
        t2 += xv.x * b2.x + xv.y * b2.y + xv.z * b2.z + xv.w * b2.w;
        t3 += xv.x * b3.x + xv.y * b3.y + xv.z * b3.z + xv.w * b3.w;
    }
    Tp[ms][0 * NF + f] = t0;
    Tp[ms][1 * NF + f] = t1;
    Tp[ms][2 * NF + f] = t2;
    Tp[ms][3 * NF + f] = t3;
    __syncthreads();

    // 3) Reduce ms partials: Tsum[c] = sum_ms Tp[ms][c]
    if (t < CC / 4) {
        const float4* r0 = (const float4*)Tp[0];
        const float4* r1 = (const float4*)Tp[1];
        const float4* r2 = (const float4*)Tp[2];
        const float4* r3 = (const float4*)Tp[3];
        float4 x0 = r0[t], x1 = r1[t], x2 = r2[t], x3 = r3[t];
        Tsum4[t] = make_float4(x0.x + x1.x + x2.x + x3.x,
                               x0.y + x1.y + x2.y + x3.y,
                               x0.z + x1.z + x2.z + x3.z,
                               x0.w + x1.w + x2.w + x3.w);
    }
    __syncthreads();

    // 4) partial y[o] = sum_c fc_w[o,c] * Tsum[c]; accumulate into out.
    if (t < NOUT) {
        float acc = 0.f;
#pragma unroll 8
        for (int i = 0; i < CC / 4; ++i) {
            float4 wv = fcw4[(size_t)t * (CC / 4) + i];
            float4 sv = Tsum4[i];
            acc += wv.x * sv.x + wv.y * sv.y + wv.z * sv.z + wv.w * sv.w;
        }
        atomicAdd(&out[b * NOUT + t], acc);
    }
}

extern "C" void kernel_launch(void* const* d_in, const int* in_sizes, int n_in,
                              void* d_out, int out_size, void* d_ws, size_t ws_size,
                              hipStream_t stream) {
    // Inputs (setup_inputs order): X, W, fc_w, fc_b, N_batch, mask — all fp32.
    const float4* X4   = (const float4*)d_in[0];
    const float4* W4   = (const float4*)d_in[1];
    const float4* fcw4 = (const float4*)d_in[2];
    const float*  fcb  = (const float*)d_in[3];
    float* out = (float*)d_out;

    bias_init_kernel<<<(BS * NOUT) / 256, 256, 0, stream>>>(fcb, out);
    fused_kernel<<<BS * NC, 256, 0, stream>>>(W4, X4, fcw4, out);
}

// Round 4
// 210.592 us; speedup vs baseline: 1.0564x; 1.0564x over previous
//
#include <hip/hip_runtime.h>

// Problem dims (fixed by reference setup_inputs)
#define BS   32
#define NF   64     // n_feat
#define NN   512    // N
#define JJ   4      // J
#define NOUT 128
#define CC   256    // J*NF
#define NC   8      // n-chunks in phase 1
#define ROWS 64     // NN/NC rows per chunk
#define MJC  2      // mj-chunks per row
#define ROW4 512    // float4 per (b,n) row  (NN*JJ/4)
#define CH4  256    // float4 per mj-chunk

// Phase 1: pure streaming partial column-sums of W over n. (No barriers, no
// LDS — keeps HBM issue dense; fusing compute here regressed, see R3.)
// W flat index = ((b*NN + n)*NN + m)*JJ + j  -> as float4: (b*NN + n)*ROW4 + m
// P4[(b*NC + nc)*ROW4 + m] = sum_{n in chunk nc} W4[(b*NN + n)*ROW4 + m]
__global__ __launch_bounds__(256) void sumW_kernel(const float4* __restrict__ W4,
                                                   float4* __restrict__ P4) {
    int blk  = blockIdx.x;          // (b*NC + nc)*MJC + mjc
    int mjc  = blk & (MJC - 1);
    int rest = blk >> 1;            // MJC == 2
    int nc   = rest & (NC - 1);
    int b    = rest >> 3;           // NC == 8
    int m    = mjc * CH4 + threadIdx.x;   // float4 index within row, [0, 512)

    const float4* p = W4 + ((size_t)(b * NN + nc * ROWS)) * ROW4 + m;
    float4 acc = make_float4(0.f, 0.f, 0.f, 0.f);
#pragma unroll 8
    for (int r = 0; r < ROWS; ++r) {
        float4 v = p[(size_t)r * ROW4];
        acc.x += v.x; acc.y += v.y; acc.z += v.z; acc.w += v.w;
    }
    P4[((size_t)(b * NC + nc)) * ROW4 + m] = acc;
}

// Phase 2: one block per batch b, 1024 threads (16 waves) to cut serial depth.
//   fold P -> S   (2-way split over nc, LDS combine)
//   T[j][f] = sum_m S[j][m]*X[b,f,m]   (16-way split over 32-m segments)
//   y[o] = sum_c fc_w[o,c]*T[c] + N*fc_b[o]   (8-way split + shfl reduce)
__global__ __launch_bounds__(1024) void finish_kernel(const float4* __restrict__ P4,
                                                      const float4* __restrict__ X4,
                                                      const float4* __restrict__ fcw4,
                                                      const float* __restrict__ fcb,
                                                      float* __restrict__ out) {
    // S[j][seg][i]: m = seg*32 + i. Pad 36 -> seg stride = 144 B = bank+4 mod 32,
    // so the 16 concurrent segment readers alias banks only 2-way (free).
    __shared__ __align__(16) float S[JJ][16][36];
    __shared__ __align__(16) float4 Fold[NN];     // 8 KB scratch for nc-fold
    __shared__ __align__(16) float Tp[16][CC];    // per-segment partial T
    __shared__ __align__(16) float4 Tsum4[CC / 4];

    int b = blockIdx.x;
    int t = threadIdx.x;

    // 1) Fold NC=8 partials. t<512: nc 0..3 for m=t; t>=512: nc 4..7 for m=t-512.
    {
        int m = t & (NN - 1);
        int h = t >> 9;   // 0 or 1
        const float4* pp = P4 + ((size_t)(b * NC + h * 4)) * ROW4 + m;
        float4 a = make_float4(0.f, 0.f, 0.f, 0.f);
#pragma unroll
        for (int k = 0; k < 4; ++k) {
            float4 v = pp[(size_t)k * ROW4];
            a.x += v.x; a.y += v.y; a.z += v.z; a.w += v.w;
        }
        if (h) Fold[m] = a;
        __syncthreads();
        if (!h) {
            float4 o = Fold[m];
            a.x += o.x; a.y += o.y; a.z += o.z; a.w += o.w;
            int seg = m >> 5, i = m & 31;
            S[0][seg][i] = a.x; S[1][seg][i] = a.y;
            S[2][seg][i] = a.z; S[3][seg][i] = a.w;
        }
        __syncthreads();
    }

    // 2) Partial T over 32-m segment: f = t>>4 (64), seg = t&15 (16).
    {
        int f = t >> 4, seg = t & 15;
        const float4* xp = X4 + ((size_t)(b * NF + f)) * (NN / 4) + seg * 8;
        const float4* s0 = (const float4*)(&S[0][seg][0]);
        const float4* s1 = (const float4*)(&S[1][seg][0]);
        const float4* s2 = (const float4*)(&S[2][seg][0]);
        const float4* s3 = (const float4*)(&S[3][seg][0]);
        float t0 = 0.f, t1 = 0.f, t2 = 0.f, t3 = 0.f;
#pragma unroll
        for (int i = 0; i < 8; ++i) {
            float4 xv = xp[i];
            float4 b0 = s0[i], b1 = s1[i], b2 = s2[i], b3 = s3[i];
            t0 += xv.x * b0.x + xv.y * b0.y + xv.z * b0.z + xv.w * b0.w;
            t1 += xv.x * b1.x + xv.y * b1.y + xv.z * b1.z + xv.w * b1.w;
            t2 += xv.x * b2.x + xv.y * b2.y + xv.z * b2.z + xv.w * b2.w;
            t3 += xv.x * b3.x + xv.y * b3.y + xv.z * b3.z + xv.w * b3.w;
        }
        Tp[seg][0 * NF + f] = t0;
        Tp[seg][1 * NF + f] = t1;
        Tp[seg][2 * NF + f] = t2;
        Tp[seg][3 * NF + f] = t3;
    }
    __syncthreads();

    // 3) Tsum[c] = sum_seg Tp[seg][c]  (lanes stride consecutively: no conflicts)
    if (t < CC) {
        float a = 0.f;
#pragma unroll
        for (int s = 0; s < 16; ++s) a += Tp[s][t];
        ((float*)Tsum4)[t] = a;
    }
    __syncthreads();

    // 4) y: o = t>>3, k = t&7; each handles 8 of the 64 c-float4s, shfl-reduce.
    {
        int o = t >> 3, k = t & 7;
        const float4* wp = fcw4 + (size_t)o * (CC / 4) + k * 8;
        float acc = 0.f;
#pragma unroll
        for (int u = 0; u < 8; ++u) {
            float4 wv = wp[u];
            float4 sv = Tsum4[k * 8 + u];
            acc += wv.x * sv.x + wv.y * sv.y + wv.z * sv.z + wv.w * sv.w;
        }
        acc += __shfl_down(acc, 4, 8);
        acc += __shfl_down(acc, 2, 8);
        acc += __shfl_down(acc, 1, 8);
        if (k == 0) out[b * NOUT + o] = acc + (float)NN * fcb[o];
    }
}

extern "C" void kernel_launch(void* const* d_in, const int* in_sizes, int n_in,
                              void* d_out, int out_size, void* d_ws, size_t ws_size,
                              hipStream_t stream) {
    // Inputs (setup_inputs order): X, W, fc_w, fc_b, N_batch, mask — all fp32.
    const float4* X4   = (const float4*)d_in[0];
    const float4* W4   = (const float4*)d_in[1];
    const float4* fcw4 = (const float4*)d_in[2];
    const float*  fcb  = (const float*)d_in[3];
    float* out = (float*)d_out;

    // Workspace: P partials, BS*NC*ROW4 float4 = 2 MiB. Fully overwritten by
    // sumW_kernel before finish_kernel reads it (0xAA poison is harmless).
    float4* P4 = (float4*)d_ws;

    sumW_kernel<<<BS * NC * MJC, 256, 0, stream>>>(W4, P4);
    finish_kernel<<<BS, 1024, 0, stream>>>(P4, X4, fcw4, fcb, out);
}